// Round 14
// baseline (95.078 us; speedup 1.0000x reference)
//
#include <hip/hip_runtime.h>

typedef unsigned long long u64;

#define CSC 2.8853900817779268f   // 2*log2(e): tanh(x) = 1 - 2/(exp2(x*CSC)+1)
#define NBIN 4096
#define CAP  256
#define SNB  64                   // n per scores block
#define SBB  32                   // baskets per scores block
#define MAXJ 16                   // select supports N <= 16*4096

// ---------- sortable key packing ----------
__device__ __forceinline__ unsigned ord32(float f) {
  unsigned u = __float_as_uint(f);
  return (u & 0x80000000u) ? ~u : (u | 0x80000000u);
}
// max-key: descending score, ties -> ascending index (jax.lax.top_k semantics)
__device__ __forceinline__ u64 packMax(float f, int n) {
  return ((u64)ord32(f) << 32) | (unsigned)(~(unsigned)n);
}

// ================= prep: 4x4 register-tiled projection (r7 exact) =================
__global__ void __launch_bounds__(256)
prep_kernel(const float* __restrict__ basket, const float* __restrict__ item,
            const float* __restrict__ Wb, const float* __restrict__ Wi,
            float* __restrict__ ipE, float* __restrict__ bpE,
            int N, int B, int nItemBlk) {
  __shared__ float itS[64][64];   // [e][row]
  __shared__ float WT[64][64];    // [e][d]
  int tid = threadIdx.x;

  bool isBasket = (blockIdx.x >= nItemBlk);
  const float* src = isBasket ? basket : item;
  const float* W   = isBasket ? Wb : Wi;
  float* dst       = isBasket ? bpE : ipE;
  int r0   = isBasket ? (blockIdx.x - nItemBlk) * 64 : blockIdx.x * 64;
  int rMax = isBasket ? B : N;

  {
    int r = tid & 63, ec = (tid >> 6) * 16;
    const float4* sp = (const float4*)(src + (size_t)(r0 + r) * 64 + ec);
    bool ok = (r0 + r) < rMax;
#pragma unroll
    for (int q = 0; q < 4; ++q) {
      float4 t = ok ? sp[q] : make_float4(0.f, 0.f, 0.f, 0.f);
      itS[ec + 4 * q + 0][r] = t.x;
      itS[ec + 4 * q + 1][r] = t.y;
      itS[ec + 4 * q + 2][r] = t.z;
      itS[ec + 4 * q + 3][r] = t.w;
    }
    const float4* wp = (const float4*)(W + (size_t)r * 64 + ec);
#pragma unroll
    for (int q = 0; q < 4; ++q) {
      float4 t = wp[q];
      WT[ec + 4 * q + 0][r] = t.x;
      WT[ec + 4 * q + 1][r] = t.y;
      WT[ec + 4 * q + 2][r] = t.z;
      WT[ec + 4 * q + 3][r] = t.w;
    }
  }
  __syncthreads();

  int ti = tid & 15, td = tid >> 4;
  float acc[4][4];
#pragma unroll
  for (int i = 0; i < 4; ++i)
#pragma unroll
    for (int j = 0; j < 4; ++j) acc[i][j] = 0.f;

#pragma unroll 8
  for (int e = 0; e < 64; ++e) {
    float4 ri = *(const float4*)&itS[e][4 * ti];
    float4 wd = *(const float4*)&WT[e][4 * td];
    float rr[4] = {ri.x, ri.y, ri.z, ri.w};
    float ww[4] = {wd.x, wd.y, wd.z, wd.w};
#pragma unroll
    for (int i = 0; i < 4; ++i)
#pragma unroll
      for (int j = 0; j < 4; ++j) acc[i][j] = fmaf(rr[i], ww[j], acc[i][j]);
  }

#pragma unroll
  for (int i = 0; i < 4; ++i) {
    int gr = r0 + 4 * ti + i;
    if (gr < rMax) {
      float4 o;
      o.x = __builtin_amdgcn_exp2f(acc[i][0] * CSC);
      o.y = __builtin_amdgcn_exp2f(acc[i][1] * CSC);
      o.z = __builtin_amdgcn_exp2f(acc[i][2] * CSC);
      o.w = __builtin_amdgcn_exp2f(acc[i][3] * CSC);
      *(float4*)(dst + (size_t)gr * 64 + 4 * td) = o;
    }
  }
}

// ================= scores: d-slice decomposition =================
// thread (ni, ds): ni = n within tile, ds = 16-d slice. eh[16] loaded ONCE;
// acc[32] basket partials (non-rematerializable). LDS fold across 4 slices.
__global__ void __launch_bounds__(256)
scores_kernel(const float* __restrict__ ipE, const float* __restrict__ bpE,
              const float* __restrict__ v, float* __restrict__ scores, int N, int B) {
  __shared__ float part[4][SBB][SNB];   // 32 KB
  int tid = threadIdx.x;
  int ni = tid & 63;
  int ds = __builtin_amdgcn_readfirstlane(tid >> 6);   // wave-uniform slice id
  int n0 = blockIdx.x * SNB;
  int b0 = blockIdx.y * SBB;
  int n = n0 + ni;

  float svf;
  {
    double sv = 0.0;
#pragma unroll
    for (int d = 0; d < 64; ++d) sv += (double)v[d];   // uniform -> s_load
    svf = (float)sv;
  }

  float eh[16];
  if (n < N) {
    const float4* p = (const float4*)(ipE + (size_t)n * 64 + ds * 16);
#pragma unroll
    for (int i = 0; i < 4; ++i) {
      float4 t = p[i];
      eh[4 * i] = t.x; eh[4 * i + 1] = t.y; eh[4 * i + 2] = t.z; eh[4 * i + 3] = t.w;
    }
  } else {
#pragma unroll
    for (int i = 0; i < 16; ++i) eh[i] = 0.f;          // benign filler
  }
  const float* vh = v + ds * 16;                       // uniform -> s_load

  float acc[SBB];
#pragma unroll
  for (int b = 0; b < SBB; ++b) {
    const float* eb = bpE + (size_t)(b0 + b) * 64 + ds * 16;  // uniform -> s_load
    float a = 0.f;
#pragma unroll
    for (int h = 0; h < 4; ++h) {          // 4-term rational subgroups (r9 chain order)
      int q0 = h * 4;
      float x0 = fmaf(eb[q0 + 0], eh[q0 + 0], 1.0f);
      float x1 = fmaf(eb[q0 + 1], eh[q0 + 1], 1.0f);
      float x2 = fmaf(eb[q0 + 2], eh[q0 + 2], 1.0f);
      float x3 = fmaf(eb[q0 + 3], eh[q0 + 3], 1.0f);
      float p01 = x0 * x1, p23 = x2 * x3;
      float den = p01 * p23;
      float n01 = vh[q0 + 0] * x1;
      n01 = fmaf(vh[q0 + 1], x0, n01);
      float n23 = vh[q0 + 2] * x3;
      n23 = fmaf(vh[q0 + 3], x2, n23);
      float num = n01 * p23;
      num = fmaf(n23, p01, num);
      float r = __builtin_amdgcn_rcpf(den);            // 1 rcp per 4 terms
      a = fmaf(num, r, a);
    }
    acc[b] = a;
  }

#pragma unroll
  for (int b = 0; b < SBB; ++b) part[ds][b][ni] = acc[b];   // conflict-free
  __syncthreads();

  // fold 4 slices + store; wave k covers one b-row of 64 consecutive n -> coalesced
#pragma unroll
  for (int k = 0; k < 8; ++k) {
    int pidx = tid + k * 256;
    int b = pidx >> 6, nn = pidx & 63;
    if (n0 + nn < N) {
      float t = ((part[0][b][nn] + part[1][b][nn]) + part[2][b][nn]) + part[3][b][nn];
      scores[(size_t)(b0 + b) * N + n0 + nn] = fmaf(-2.0f, t, svf);
    }
  }
}

// ================= select: sign-split, 2 blocks per row (r13, unchanged) =================
__global__ void __launch_bounds__(1024)
select_kernel(const float* __restrict__ scores, const float* __restrict__ v,
              int* __restrict__ out, int N, int B, int K) {
  __shared__ int lh[NBIN];
  __shared__ int part[64];
  __shared__ u64 cand[CAP];
  __shared__ int cnt, hHi;
  int tid = threadIdx.x;
  int b = blockIdx.x >> 1, side = blockIdx.x & 1;
  const float* row = scores + (size_t)b * N;
  float sgn = side ? -1.f : 1.f;      // side 1: top-k of -s == bottom-k of s

  for (int i = tid; i < NBIN; i += 1024) lh[i] = 0;
  if (tid == 0) cnt = 0;

  // |score| < R = sum|v_d| strictly (|tanh|<1) -> linear bins over [-R, R]
  float R = 0.f;
#pragma unroll
  for (int d = 0; d < 64; ++d) R += fabsf(v[d]);     // uniform
  float invW = (float)NBIN / (2.f * R);
  __syncthreads();

  // pass 1: load (sign-applied) into REGISTERS + histogram
  float4 v4[MAXJ];
#pragma unroll
  for (int j = 0; j < MAXJ; ++j) {
    int f4 = j * 1024 + tid;
    if (j * 4096 < N && f4 * 4 < N) {
      float4 s4 = *(const float4*)(row + (size_t)f4 * 4);
      s4.x *= sgn; s4.y *= sgn; s4.z *= sgn; s4.w *= sgn;
      v4[j] = s4;
      int n0 = f4 * 4;
      float ss[4] = {s4.x, s4.y, s4.z, s4.w};
#pragma unroll
      for (int c = 0; c < 4; ++c) {
        if (n0 + c < N) {
          int bi = (int)((ss[c] + R) * invW);
          bi = bi < 0 ? 0 : (bi > NBIN - 1 ? NBIN - 1 : bi);
          atomicAdd(&lh[bi], 1);
        }
      }
    }
  }
  __syncthreads();

  if (tid < 64) {                  // 64-bin chunk sums
    int s = 0;
    for (int jj = 0; jj < 64; ++jj) s += lh[tid * 64 + jj];
    part[tid] = s;
  }
  __syncthreads();
  if (tid == 0) {                  // threshold bin from the top (of s')
    int cum = 0, c = 63;
    for (; c > 0; --c) { if (cum + part[c] >= K) break; cum += part[c]; }
    int hh = c * 64 + 63;
    for (;; --hh) { cum += lh[hh]; if (cum >= K || hh == 0) break; }
    hHi = hh;
  }
  __syncthreads();
  int hi = hHi;

  // pass 2: compact from registers
#pragma unroll
  for (int j = 0; j < MAXJ; ++j) {
    int f4 = j * 1024 + tid;
    if (j * 4096 < N && f4 * 4 < N) {
      int n0 = f4 * 4;
      float ss[4] = {v4[j].x, v4[j].y, v4[j].z, v4[j].w};
#pragma unroll
      for (int c = 0; c < 4; ++c) {
        if (n0 + c < N) {
          float s = ss[c];
          int bi = (int)((s + R) * invW);
          bi = bi < 0 ? 0 : (bi > NBIN - 1 ? NBIN - 1 : bi);
          if (bi >= hi) { int i = atomicAdd(&cnt, 1); if (i < CAP) cand[i] = packMax(s, n0 + c); }
        }
      }
    }
  }
  __syncthreads();

  // exact rank, O(C^2); keys unique -> ranks unique & complete
  int tP = cnt < CAP ? cnt : CAP;
  int* dst = out + (side ? (size_t)B * K : 0) + (size_t)b * K;
  for (int i = tid; i < tP; i += 1024) {
    u64 key = cand[i]; int r = 0;
    for (int jj = 0; jj < tP; ++jj) r += (cand[jj] > key);
    if (r < K) dst[r] = (int)(~(unsigned)key);
  }
}

extern "C" void kernel_launch(void* const* d_in, const int* in_sizes, int n_in,
                              void* d_out, int out_size, void* d_ws, size_t ws_size,
                              hipStream_t stream) {
  const float* basket = (const float*)d_in[0];
  const float* item   = (const float*)d_in[1];
  const float* Wb     = (const float*)d_in[2];
  const float* Wi     = (const float*)d_in[3];
  const float* v      = (const float*)d_in[4];
  int D = in_sizes[4];           // 64
  int B = in_sizes[0] / D;       // 128
  int N = in_sizes[1] / D;       // 50000
  int K = out_size / (2 * B);    // 50

  float* scores = (float*)d_ws;                         // B*N floats = 25.6 MB
  float* ipE    = scores + (size_t)B * N;               // N*64 floats = 12.8 MB
  float* bpE    = ipE + (size_t)N * 64;                 // B*64 floats = 32 KB

  int nItemBlk = (N + 63) / 64;
  int nBasBlk  = (B + 63) / 64;
  prep_kernel<<<dim3(nItemBlk + nBasBlk), dim3(256), 0, stream>>>(basket, item, Wb, Wi, ipE, bpE, N, B, nItemBlk);

  dim3 gs((N + SNB - 1) / SNB, (B + SBB - 1) / SBB);
  scores_kernel<<<gs, dim3(256), 0, stream>>>(ipE, bpE, v, scores, N, B);

  select_kernel<<<dim3(2 * B), dim3(1024), 0, stream>>>(scores, v, (int*)d_out, N, B, K);
}

// Round 15
// 74.721 us; speedup vs baseline: 1.2724x; 1.2724x over previous
//
#include <hip/hip_runtime.h>

typedef unsigned long long u64;
typedef float f32x2 __attribute__((ext_vector_type(2)));

#define CSC 2.8853900817779268f   // 2*log2(e): tanh(x) = 1 - 2/(exp2(x*CSC)+1)
#define NBIN 4096
#define CAP  256
#define BT   8
#define MAXJ 16                   // select supports N <= 16*4096

__device__ __forceinline__ f32x2 fma2(f32x2 a, f32x2 b, f32x2 c) {
#if __has_builtin(__builtin_elementwise_fma)
  return __builtin_elementwise_fma(a, b, c);   // -> v_pk_fma_f32
#else
  f32x2 r; r.x = fmaf(a.x, b.x, c.x); r.y = fmaf(a.y, b.y, c.y); return r;
#endif
}

// ---------- sortable key packing ----------
__device__ __forceinline__ unsigned ord32(float f) {
  unsigned u = __float_as_uint(f);
  return (u & 0x80000000u) ? ~u : (u | 0x80000000u);
}
// max-key: descending score, ties -> ascending index (jax.lax.top_k semantics)
__device__ __forceinline__ u64 packMax(float f, int n) {
  return ((u64)ord32(f) << 32) | (unsigned)(~(unsigned)n);
}

// ================= prep: 4x4 register-tiled projection, SWAPPED pk layout =================
// positions (p0,p1,p2,p3) hold orig d (p0, p0+2, p0+1, p0+3); also writes swapped vS.
// (layout + numerics correctness-proven in r12, absmax 0)
__global__ void __launch_bounds__(256)
prep_kernel(const float* __restrict__ basket, const float* __restrict__ item,
            const float* __restrict__ Wb, const float* __restrict__ Wi,
            const float* __restrict__ v,
            float* __restrict__ ipE, float* __restrict__ bpE, float* __restrict__ vS,
            int N, int B, int nItemBlk) {
  __shared__ float itS[64][64];   // [e][row]
  __shared__ float WT[64][64];    // [e][d]
  int tid = threadIdx.x;

  bool isBasket = (blockIdx.x >= nItemBlk);
  const float* src = isBasket ? basket : item;
  const float* W   = isBasket ? Wb : Wi;
  float* dst       = isBasket ? bpE : ipE;
  int r0   = isBasket ? (blockIdx.x - nItemBlk) * 64 : blockIdx.x * 64;
  int rMax = isBasket ? B : N;

  if (blockIdx.x == (unsigned)nItemBlk && tid < 64) {  // swapped v copy
    int q = tid & 3;
    int sidx = tid + (q == 1 ? 1 : 0) - (q == 2 ? 1 : 0);
    vS[tid] = v[sidx];
  }

  {
    int r = tid & 63, ec = (tid >> 6) * 16;
    const float4* sp = (const float4*)(src + (size_t)(r0 + r) * 64 + ec);
    bool ok = (r0 + r) < rMax;
#pragma unroll
    for (int q = 0; q < 4; ++q) {
      float4 t = ok ? sp[q] : make_float4(0.f, 0.f, 0.f, 0.f);
      itS[ec + 4 * q + 0][r] = t.x;
      itS[ec + 4 * q + 1][r] = t.y;
      itS[ec + 4 * q + 2][r] = t.z;
      itS[ec + 4 * q + 3][r] = t.w;
    }
    const float4* wp = (const float4*)(W + (size_t)r * 64 + ec);
#pragma unroll
    for (int q = 0; q < 4; ++q) {
      float4 t = wp[q];
      WT[ec + 4 * q + 0][r] = t.x;
      WT[ec + 4 * q + 1][r] = t.y;
      WT[ec + 4 * q + 2][r] = t.z;
      WT[ec + 4 * q + 3][r] = t.w;
    }
  }
  __syncthreads();

  int ti = tid & 15, td = tid >> 4;
  float acc[4][4];
#pragma unroll
  for (int i = 0; i < 4; ++i)
#pragma unroll
    for (int j = 0; j < 4; ++j) acc[i][j] = 0.f;

#pragma unroll 8
  for (int e = 0; e < 64; ++e) {
    float4 ri = *(const float4*)&itS[e][4 * ti];
    float4 wd = *(const float4*)&WT[e][4 * td];
    float rr[4] = {ri.x, ri.y, ri.z, ri.w};
    float ww[4] = {wd.x, wd.y, wd.z, wd.w};
#pragma unroll
    for (int i = 0; i < 4; ++i)
#pragma unroll
      for (int j = 0; j < 4; ++j) acc[i][j] = fmaf(rr[i], ww[j], acc[i][j]);
  }

#pragma unroll
  for (int i = 0; i < 4; ++i) {
    int gr = r0 + 4 * ti + i;
    if (gr < rMax) {
      float4 o;                   // middle-two swapped: (d0, d2, d1, d3)
      o.x = __builtin_amdgcn_exp2f(acc[i][0] * CSC);
      o.y = __builtin_amdgcn_exp2f(acc[i][2] * CSC);
      o.z = __builtin_amdgcn_exp2f(acc[i][1] * CSC);
      o.w = __builtin_amdgcn_exp2f(acc[i][3] * CSC);
      *(float4*)(dst + (size_t)gr * 64 + 4 * td) = o;
    }
  }
}

// ================= scores: pk 4-term rational + split-d halves, no LDS =================
__global__ void __launch_bounds__(256)
scores_kernel(const float* __restrict__ ipE, const float* __restrict__ bpE,
              const float* __restrict__ v, const float* __restrict__ vS,
              float* __restrict__ scores, int N, int B) {
  int tid = threadIdx.x;
  int b0 = blockIdx.y * BT;
  if (b0 > B - BT) b0 = B - BT;              // duplicate-safe clamp
  int n = blockIdx.x * 256 + tid;
  if (n >= N) return;

  float svf;
  {
    double sv = 0.0;
#pragma unroll
    for (int d = 0; d < 64; ++d) sv += (double)v[d]; // uniform, original order
    svf = (float)sv;
  }

  float acc[BT];
#pragma unroll
  for (int b = 0; b < BT; ++b) acc[b] = 0.f;

  f32x2 one2; one2.x = 1.f; one2.y = 1.f;

#pragma unroll
  for (int half = 0; half < 2; ++half) {
    // 16 f32x2 pairs (32 VGPR): A-pairs (d0,d2), B-pairs (d1,d3) per aligned-4 group
    f32x2 eh2[16];
    const f32x2* p = (const f32x2*)(ipE + (size_t)n * 64 + half * 32);
#pragma unroll
    for (int i = 0; i < 16; ++i) eh2[i] = p[i];
    const f32x2* vv2 = (const f32x2*)(vS + half * 32);  // uniform -> s_load

#pragma unroll
    for (int b = 0; b < BT; ++b) {
      const f32x2* eb2 = (const f32x2*)(bpE + (size_t)(b0 + b) * 64 + half * 32); // uniform
      float a = acc[b];
#pragma unroll
      for (int g = 0; g < 8; ++g) {       // 4 orig-d terms per group
        f32x2 XA = fma2(eb2[2 * g], eh2[2 * g], one2);          // (x0, x2)
        f32x2 XB = fma2(eb2[2 * g + 1], eh2[2 * g + 1], one2);  // (x1, x3)
        f32x2 PP = XA * XB;                                     // (x0x1, x2x3)
        f32x2 T  = vv2[2 * g] * XB;                             // (v0x1, v2x3)
        f32x2 NUM = fma2(vv2[2 * g + 1], XA, T);                // (n01, n23)
        float den = PP.x * PP.y;
        float num = NUM.x * PP.y;
        num = fmaf(NUM.y, PP.x, num);
        float r = __builtin_amdgcn_rcpf(den);                   // 1 rcp per 4 terms
        a = fmaf(num, r, a);
      }
      acc[b] = a;
    }
  }

#pragma unroll
  for (int b = 0; b < BT; ++b)
    scores[(size_t)(b0 + b) * N + n] = fmaf(-2.0f, acc[b], svf);
}

// ================= select: sign-split, 2 blocks per row (r13, unchanged) =================
__global__ void __launch_bounds__(1024)
select_kernel(const float* __restrict__ scores, const float* __restrict__ v,
              int* __restrict__ out, int N, int B, int K) {
  __shared__ int lh[NBIN];
  __shared__ int part[64];
  __shared__ u64 cand[CAP];
  __shared__ int cnt, hHi;
  int tid = threadIdx.x;
  int b = blockIdx.x >> 1, side = blockIdx.x & 1;
  const float* row = scores + (size_t)b * N;
  float sgn = side ? -1.f : 1.f;      // side 1: top-k of -s == bottom-k of s

  for (int i = tid; i < NBIN; i += 1024) lh[i] = 0;
  if (tid == 0) cnt = 0;

  // |score| < R = sum|v_d| strictly (|tanh|<1) -> linear bins over [-R, R]
  float R = 0.f;
#pragma unroll
  for (int d = 0; d < 64; ++d) R += fabsf(v[d]);     // uniform
  float invW = (float)NBIN / (2.f * R);
  __syncthreads();

  // pass 1: load (sign-applied) into REGISTERS + histogram
  float4 v4[MAXJ];
#pragma unroll
  for (int j = 0; j < MAXJ; ++j) {
    int f4 = j * 1024 + tid;
    if (j * 4096 < N && f4 * 4 < N) {
      float4 s4 = *(const float4*)(row + (size_t)f4 * 4);
      s4.x *= sgn; s4.y *= sgn; s4.z *= sgn; s4.w *= sgn;
      v4[j] = s4;
      int n0 = f4 * 4;
      float ss[4] = {s4.x, s4.y, s4.z, s4.w};
#pragma unroll
      for (int c = 0; c < 4; ++c) {
        if (n0 + c < N) {
          int bi = (int)((ss[c] + R) * invW);
          bi = bi < 0 ? 0 : (bi > NBIN - 1 ? NBIN - 1 : bi);
          atomicAdd(&lh[bi], 1);
        }
      }
    }
  }
  __syncthreads();

  if (tid < 64) {                  // 64-bin chunk sums
    int s = 0;
    for (int jj = 0; jj < 64; ++jj) s += lh[tid * 64 + jj];
    part[tid] = s;
  }
  __syncthreads();
  if (tid == 0) {                  // threshold bin from the top (of s')
    int cum = 0, c = 63;
    for (; c > 0; --c) { if (cum + part[c] >= K) break; cum += part[c]; }
    int hh = c * 64 + 63;
    for (;; --hh) { cum += lh[hh]; if (cum >= K || hh == 0) break; }
    hHi = hh;
  }
  __syncthreads();
  int hi = hHi;

  // pass 2: compact from registers
#pragma unroll
  for (int j = 0; j < MAXJ; ++j) {
    int f4 = j * 1024 + tid;
    if (j * 4096 < N && f4 * 4 < N) {
      int n0 = f4 * 4;
      float ss[4] = {v4[j].x, v4[j].y, v4[j].z, v4[j].w};
#pragma unroll
      for (int c = 0; c < 4; ++c) {
        if (n0 + c < N) {
          float s = ss[c];
          int bi = (int)((s + R) * invW);
          bi = bi < 0 ? 0 : (bi > NBIN - 1 ? NBIN - 1 : bi);
          if (bi >= hi) { int i = atomicAdd(&cnt, 1); if (i < CAP) cand[i] = packMax(s, n0 + c); }
        }
      }
    }
  }
  __syncthreads();

  // exact rank, O(C^2); keys unique -> ranks unique & complete
  int tP = cnt < CAP ? cnt : CAP;
  int* dst = out + (side ? (size_t)B * K : 0) + (size_t)b * K;
  for (int i = tid; i < tP; i += 1024) {
    u64 key = cand[i]; int r = 0;
    for (int jj = 0; jj < tP; ++jj) r += (cand[jj] > key);
    if (r < K) dst[r] = (int)(~(unsigned)key);
  }
}

extern "C" void kernel_launch(void* const* d_in, const int* in_sizes, int n_in,
                              void* d_out, int out_size, void* d_ws, size_t ws_size,
                              hipStream_t stream) {
  const float* basket = (const float*)d_in[0];
  const float* item   = (const float*)d_in[1];
  const float* Wb     = (const float*)d_in[2];
  const float* Wi     = (const float*)d_in[3];
  const float* v      = (const float*)d_in[4];
  int D = in_sizes[4];           // 64
  int B = in_sizes[0] / D;       // 128
  int N = in_sizes[1] / D;       // 50000
  int K = out_size / (2 * B);    // 50

  float* scores = (float*)d_ws;                         // B*N floats = 25.6 MB
  float* ipE    = scores + (size_t)B * N;               // N*64 floats = 12.8 MB
  float* bpE    = ipE + (size_t)N * 64;                 // B*64 floats = 32 KB
  float* vS     = bpE + (size_t)B * 64;                 // 64 floats (swapped v)

  int nItemBlk = (N + 63) / 64;
  int nBasBlk  = (B + 63) / 64;
  prep_kernel<<<dim3(nItemBlk + nBasBlk), dim3(256), 0, stream>>>(basket, item, Wb, Wi, v, ipE, bpE, vS, N, B, nItemBlk);

  dim3 gs((N + 255) / 256, (B + BT - 1) / BT);
  scores_kernel<<<gs, dim3(256), 0, stream>>>(ipE, bpE, v, vS, scores, N, B);

  select_kernel<<<dim3(2 * B), dim3(1024), 0, stream>>>(scores, v, (int*)d_out, N, B, K);
}